// Round 1
// baseline (104.455 us; speedup 1.0000x reference)
//
#include <hip/hip_runtime.h>

// DigitCaps dynamic routing, fully fused: one block per batch element.
// Key algebra: u_hat is never materialized.
//   s[o,p]   = sum_{c,q} Wm[c,o,p,q] * t[c,o,q],  t[c,o,q] = sum_hw c_ij * u
//   logits   = u . Wv_acc,  Wv_acc[c,o,q] = sum_iters sum_p Wm[c,o,p,q]*v[o,p]
// Iter 1: c_ij uniform = 0.1 -> s1 = 0.1 * Wm . (sum_hw u)

#define BB 128
#define CC 32
#define HWN 144   // 12*12
#define QQ 8      // IN_CAPS
#define OO 10     // OUT_CH
#define PP 16     // OUT_CAPS

__global__ __launch_bounds__(256, 1)
void digitcaps_routing(const float* __restrict__ x, const float* __restrict__ Wm,
                       float* __restrict__ out) {
    const int b    = blockIdx.x;
    const int tid  = threadIdx.x;
    const int c    = tid >> 3;   // 0..31
    const int slot = tid & 7;    // 0..7

    __shared__ float usum_s[CC * QQ];        // 256 f
    __shared__ float Wv_s[CC * OO * QQ];     // 2560 f (running Wv accumulator)
    __shared__ float t_s[CC * OO * QQ];      // 2560 f
    __shared__ float v_s[OO * PP];           // 160 f

    const float* xb = x + (size_t)b * (CC * HWN * QQ);
    const float* xc = xb + c * (HWN * QQ);

    // ---- Step A: usum[c][q] = sum_hw x[b,c,hw,q] ----
    float us[QQ];
#pragma unroll
    for (int q = 0; q < QQ; ++q) us[q] = 0.f;
#pragma unroll
    for (int i = 0; i < 18; ++i) {
        const int hw = slot + (i << 3);
        const float4* p4 = (const float4*)(xc + hw * QQ);
        float4 a = p4[0], d = p4[1];
        us[0] += a.x; us[1] += a.y; us[2] += a.z; us[3] += a.w;
        us[4] += d.x; us[5] += d.y; us[6] += d.z; us[7] += d.w;
    }
    // reduce over the 8 slot lanes (contiguous lanes within the wave)
#pragma unroll
    for (int m = 1; m <= 4; m <<= 1) {
#pragma unroll
        for (int q = 0; q < QQ; ++q) us[q] += __shfl_xor(us[q], m);
    }
    if (slot == 0) {
#pragma unroll
        for (int q = 0; q < QQ; ++q) usum_s[c * QQ + q] = us[q];
    }
    __syncthreads();

    // ---- Step B: s1 = 0.1 * Wm . usum ; v1 = squash(s1) ----
    if (tid < OO * PP) {
        const int o = tid >> 4, p = tid & 15;
        float s = 0.f;
        for (int cc = 0; cc < CC; ++cc) {
            const float4* w4 = (const float4*)(Wm + (((cc * OO + o) * PP + p) * QQ));
            float4 w0 = w4[0], w1 = w4[1];
            const float* u0 = &usum_s[cc * QQ];
            s += w0.x * u0[0] + w0.y * u0[1] + w0.z * u0[2] + w0.w * u0[3]
               + w1.x * u0[4] + w1.y * u0[5] + w1.z * u0[6] + w1.w * u0[7];
        }
        s *= 0.1f;
        float sn = s * s;
#pragma unroll
        for (int m = 1; m <= 8; m <<= 1) sn += __shfl_xor(sn, m);
        const float fac = sqrtf(sn) / (1.f + sn);
        v_s[tid] = s * fac;
    }
    // zero the Wv accumulator
    for (int k = tid; k < CC * OO * QQ; k += 256) Wv_s[k] = 0.f;
    __syncthreads();

    // ---- Routing iterations 2 and 3 ----
    for (int iter = 0; iter < 2; ++iter) {
        // C1: Wv_acc[c,o,q] += sum_p Wm[c,o,p,q] * v[o,p]
        for (int k = tid; k < CC * OO * QQ; k += 256) {
            const int cc  = k / (OO * QQ);
            const int rem = k - cc * (OO * QQ);
            const int o   = rem >> 3, q = rem & 7;
            const float* wp = Wm + ((cc * OO + o) * PP) * QQ + q;
            float acc = 0.f;
#pragma unroll
            for (int p = 0; p < PP; ++p) acc += wp[p * QQ] * v_s[o * PP + p];
            Wv_s[k] += acc;
        }
        __syncthreads();

        // C2: per (c,slot): logits = u.Wv_acc, softmax over o, t += c_ij*u
        float wv[OO][QQ];
#pragma unroll
        for (int o = 0; o < OO; ++o)
#pragma unroll
            for (int q = 0; q < QQ; ++q) wv[o][q] = Wv_s[(c * OO + o) * QQ + q];

        float tl[OO][QQ];
#pragma unroll
        for (int o = 0; o < OO; ++o)
#pragma unroll
            for (int q = 0; q < QQ; ++q) tl[o][q] = 0.f;

        for (int i = 0; i < 18; ++i) {
            const int hw = slot + (i << 3);
            const float4* p4 = (const float4*)(xc + hw * QQ);
            float4 a = p4[0], d = p4[1];
            float u[QQ] = {a.x, a.y, a.z, a.w, d.x, d.y, d.z, d.w};
            float lg[OO];
            float mx = -1e30f;
#pragma unroll
            for (int o = 0; o < OO; ++o) {
                float t = 0.f;
#pragma unroll
                for (int q = 0; q < QQ; ++q) t += u[q] * wv[o][q];
                lg[o] = t;
                mx = fmaxf(mx, t);
            }
            float ssum = 0.f;
#pragma unroll
            for (int o = 0; o < OO; ++o) { lg[o] = __expf(lg[o] - mx); ssum += lg[o]; }
            const float inv = 1.f / ssum;
#pragma unroll
            for (int o = 0; o < OO; ++o) {
                const float cij = lg[o] * inv;
#pragma unroll
                for (int q = 0; q < QQ; ++q) tl[o][q] += cij * u[q];
            }
        }
        // reduce t over the 8 slot lanes
#pragma unroll
        for (int m = 1; m <= 4; m <<= 1) {
#pragma unroll
            for (int o = 0; o < OO; ++o)
#pragma unroll
                for (int q = 0; q < QQ; ++q) tl[o][q] += __shfl_xor(tl[o][q], m);
        }
        if (slot == 0) {
#pragma unroll
            for (int o = 0; o < OO; ++o)
#pragma unroll
                for (int q = 0; q < QQ; ++q) t_s[(c * OO + o) * QQ + q] = tl[o][q];
        }
        __syncthreads();

        // C3: s[o,p] = sum_{c,q} Wm[c,o,p,q]*t[c,o,q] ; v = squash(s)
        if (tid < OO * PP) {
            const int o = tid >> 4, p = tid & 15;
            float s = 0.f;
            for (int cc = 0; cc < CC; ++cc) {
                const float4* w4 = (const float4*)(Wm + (((cc * OO + o) * PP + p) * QQ));
                float4 w0 = w4[0], w1 = w4[1];
                const float* t0 = &t_s[(cc * OO + o) * QQ];
                s += w0.x * t0[0] + w0.y * t0[1] + w0.z * t0[2] + w0.w * t0[3]
                   + w1.x * t0[4] + w1.y * t0[5] + w1.z * t0[6] + w1.w * t0[7];
            }
            float sn = s * s;
#pragma unroll
            for (int m = 1; m <= 8; m <<= 1) sn += __shfl_xor(sn, m);
            const float fac = sqrtf(sn) / (1.f + sn);
            const float v = s * fac;
            if (iter == 1) out[(size_t)b * (OO * PP) + tid] = v;
            else           v_s[tid] = v;
        }
        __syncthreads();
    }
}

extern "C" void kernel_launch(void* const* d_in, const int* in_sizes, int n_in,
                              void* d_out, int out_size, void* d_ws, size_t ws_size,
                              hipStream_t stream) {
    const float* x  = (const float*)d_in[0];   // [128,32,12,12,8]
    const float* Wm = (const float*)d_in[1];   // [1,1,32,10,16,8]
    float* out = (float*)d_out;                // [128,10,16]
    digitcaps_routing<<<BB, 256, 0, stream>>>(x, Wm, out);
}